// Round 15
// baseline (74.842 us; speedup 1.0000x reference)
//
#include <hip/hip_runtime.h>
#include <math.h>

namespace {

constexpr int B_ = 4, N_ = 4, C_ = 64, H_ = 128, W_ = 128;
constexpr int HW_ = H_ * W_;
constexpr int CPB = 4;               // channels per barrier window
constexpr int NWIN = C_ / CPB;       // 16 windows

// out[:, 4] = ref
__global__ __launch_bounds__(256) void copyref_kernel(const float* __restrict__ ref,
                                                      float* __restrict__ out) {
    int t = blockIdx.x * 256 + threadIdx.x;      // one float4 per thread
    int f = t * 4;
    int b = f / (C_ * HW_);
    int within = f - b * (C_ * HW_);
    float4 v = *reinterpret_cast<const float4*>(ref + (size_t)b * C_ * HW_ + within);
    *reinterpret_cast<float4*>(out + (size_t)(b * 5 + N_) * C_ * HW_ + within) = v;
}

// One thread per pixel; block = 2 rows (256 threads); full channel loop.
// Window norms = neighbor pixels' center norms, shared via LDS.
// CPB=4 channels per barrier window, double-buffered LDS slots.
// KEY ORDER (r15): prefetch loads are issued AFTER __syncthreads() — the
// barrier's implicit s_waitcnt vmcnt(0) would otherwise drain the prefetch
// with zero compute in between (m97-style stall). Now the loads overlap the
// whole compute phase and the vmcnt wait lands at the next LDS-store.
__global__ __launch_bounds__(256) void localcorr_kernel(const float* __restrict__ nbrs,
                                                        const float* __restrict__ ref,
                                                        float* __restrict__ out) {
    __shared__ float s_own[2 * CPB][4][128];   // [slot][staged row][x]
    __shared__ float s_nrm[4][128];            // per-pixel sq-norms

    const int blk = blockIdx.x;          // 0..1023
    const int ypair = blk & 63;
    const int bi = blk >> 6;
    const int i = bi & 3;
    const int b = bi >> 2;
    const int t = (int)threadIdx.x;
    const int x = t & 127;
    const int ry = t >> 7;               // 0/1, wave-uniform
    const int y0 = ypair * 2;
    const int y = y0 + ry;

    // reflect-pad (np 'reflect', pad=1)
    const int xm = (x == 0) ? 1 : x - 1;
    const int xp = (x == W_ - 1) ? W_ - 2 : x + 1;
    const int gyA = (y0 == 0) ? 1 : y0 - 1;
    const int gyC = y0 + 1;
    const int gyD = (y0 + 2 == H_) ? H_ - 2 : y0 + 2;
    const int myRowA = (ry == 0) ? gyA : gyC;   // staged row 2ry
    const int myRowB = (ry == 0) ? y0 : gyD;    // staged row 2ry+1

    const float* __restrict__ nb = nbrs + (size_t)(b * N_ + i) * C_ * HW_;
    const float* __restrict__ rp = ref + (size_t)b * C_ * HW_;
    const int offA = myRowA * W_ + x;
    const int offB = myRowB * W_ + x;
    const int offR = y * W_ + x;

    float dot[9];
#pragma unroll
    for (int k = 0; k < 9; ++k) dot[k] = 0.f;
    float nA = 0.f, nB = 0.f, r2 = 0.f;

    // ---- pass 1: dots + norms + ref2 ----
    float co0[CPB], co1[CPB], crf[CPB];
    float no0[CPB], no1[CPB], nrf[CPB];
#pragma unroll
    for (int u = 0; u < CPB; ++u) {
        const size_t co = (size_t)u * HW_;
        co0[u] = nb[co + offA]; co1[u] = nb[co + offB]; crf[u] = rp[co + offR];
    }
#pragma unroll 1
    for (int w = 0; w < NWIN; ++w) {
        const int base = (w & 1) * CPB;
#pragma unroll
        for (int u = 0; u < CPB; ++u) {
            s_own[base + u][2 * ry + 0][x] = co0[u];
            s_own[base + u][2 * ry + 1][x] = co1[u];
        }
        __syncthreads();                 // nothing in flight: drain is free
        if (w + 1 < NWIN) {              // issue next window AFTER the barrier
#pragma unroll
            for (int u = 0; u < CPB; ++u) {
                const size_t co = (size_t)((w + 1) * CPB + u) * HW_;
                no0[u] = nb[co + offA]; no1[u] = nb[co + offB]; nrf[u] = rp[co + offR];
            }
        }
#pragma unroll
        for (int u = 0; u < CPB; ++u) {
            const float w00 = s_own[base + u][ry + 0][xm], w02 = s_own[base + u][ry + 0][xp];
            const float w10 = s_own[base + u][ry + 1][xm], w12 = s_own[base + u][ry + 1][xp];
            const float w20 = s_own[base + u][ry + 2][xm], w22 = s_own[base + u][ry + 2][xp];
            float w01, w11, w21;
            if (ry == 0) { w01 = co0[u]; w11 = co1[u]; w21 = s_own[base + u][2][x]; }
            else         { w01 = s_own[base + u][1][x]; w11 = co0[u]; w21 = co1[u]; }
            const float rf = crf[u];
            nA += co0[u] * co0[u]; nB += co1[u] * co1[u]; r2 += rf * rf;
            dot[0] += rf * w00; dot[1] += rf * w01; dot[2] += rf * w02;
            dot[3] += rf * w10; dot[4] += rf * w11; dot[5] += rf * w12;
            dot[6] += rf * w20; dot[7] += rf * w21; dot[8] += rf * w22;
        }
#pragma unroll
        for (int u = 0; u < CPB; ++u) { co0[u] = no0[u]; co1[u] = no1[u]; crf[u] = nrf[u]; }
    }

    // ---- share norms, softmax in-register ----
    s_nrm[2 * ry + 0][x] = nA;
    s_nrm[2 * ry + 1][x] = nB;
    __syncthreads();
    float nk[9];
    nk[0] = s_nrm[ry + 0][xm]; nk[1] = s_nrm[ry + 0][x]; nk[2] = s_nrm[ry + 0][xp];
    nk[3] = s_nrm[ry + 1][xm]; nk[4] = s_nrm[ry + 1][x]; nk[5] = s_nrm[ry + 1][xp];
    nk[6] = s_nrm[ry + 2][xm]; nk[7] = s_nrm[ry + 2][x]; nk[8] = s_nrm[ry + 2][xp];

    const float invr = rsqrtf(fmaxf(r2, 1e-24f));
    float inv[9], d[9];
#pragma unroll
    for (int k = 0; k < 9; ++k) {
        inv[k] = rsqrtf(fmaxf(nk[k], 1e-24f));
        d[k] = dot[k] * invr * inv[k];
    }
    float mx = d[0];
#pragma unroll
    for (int k = 1; k < 9; ++k) mx = fmaxf(mx, d[k]);
    float ssum = 0.f;
#pragma unroll
    for (int k = 0; k < 9; ++k) { d[k] = __expf(d[k] - mx); ssum += d[k]; }
    const float is = 1.f / ssum;
    float wtp[9];
#pragma unroll
    for (int k = 0; k < 9; ++k) wtp[k] = d[k] * is * inv[k];

    // ---- pass 2: aggregate + wdiff + store ----
    const float* __restrict__ pm0 = nbrs + (size_t)(b * N_ + ((i + 1) & 3)) * C_ * HW_;
    const float* __restrict__ pm1 = nbrs + (size_t)(b * N_ + ((i + 2) & 3)) * C_ * HW_;
    const float* __restrict__ pm2 = nbrs + (size_t)(b * N_ + ((i + 3) & 3)) * C_ * HW_;
    float* __restrict__ op = out + (size_t)(b * 5 + i) * C_ * HW_ + offR;

    float q0c[CPB], q1c[CPB], q2c[CPB];
    float q0n[CPB], q1n[CPB], q2n[CPB];
#pragma unroll
    for (int u = 0; u < CPB; ++u) {
        const size_t co = (size_t)u * HW_;
        co0[u] = nb[co + offA]; co1[u] = nb[co + offB];
        q0c[u] = pm0[co + offR]; q1c[u] = pm1[co + offR]; q2c[u] = pm2[co + offR];
    }
#pragma unroll 1
    for (int w = 0; w < NWIN; ++w) {
        const int base = (w & 1) * CPB;
#pragma unroll
        for (int u = 0; u < CPB; ++u) {
            s_own[base + u][2 * ry + 0][x] = co0[u];
            s_own[base + u][2 * ry + 1][x] = co1[u];
        }
        __syncthreads();                 // drain free; prefetch comes after
        if (w + 1 < NWIN) {
#pragma unroll
            for (int u = 0; u < CPB; ++u) {
                const size_t co = (size_t)((w + 1) * CPB + u) * HW_;
                no0[u] = nb[co + offA]; no1[u] = nb[co + offB];
                q0n[u] = pm0[co + offR]; q1n[u] = pm1[co + offR]; q2n[u] = pm2[co + offR];
            }
        }
#pragma unroll
        for (int u = 0; u < CPB; ++u) {
            const float w00 = s_own[base + u][ry + 0][xm], w02 = s_own[base + u][ry + 0][xp];
            const float w10 = s_own[base + u][ry + 1][xm], w12 = s_own[base + u][ry + 1][xp];
            const float w20 = s_own[base + u][ry + 2][xm], w22 = s_own[base + u][ry + 2][xp];
            float w01, w11, w21;
            if (ry == 0) { w01 = co0[u]; w11 = co1[u]; w21 = s_own[base + u][2][x]; }
            else         { w01 = s_own[base + u][1][x]; w11 = co0[u]; w21 = co1[u]; }
            const float agg = wtp[0] * w00 + wtp[1] * w01 + wtp[2] * w02
                            + wtp[3] * w10 + wtp[4] * w11 + wtp[5] * w12
                            + wtp[6] * w20 + wtp[7] * w21 + wtp[8] * w22;
            const float ctr = w11;
            const float dd = ctr - 0.25f * (ctr + q0c[u] + q1c[u] + q2c[u]);
            op[(size_t)(w * CPB + u) * HW_] = agg * __expf(-dd * dd);
        }
#pragma unroll
        for (int u = 0; u < CPB; ++u) {
            co0[u] = no0[u]; co1[u] = no1[u];
            q0c[u] = q0n[u]; q1c[u] = q1n[u]; q2c[u] = q2n[u];
        }
    }
}

}  // namespace

extern "C" void kernel_launch(void* const* d_in, const int* in_sizes, int n_in,
                              void* d_out, int out_size, void* d_ws, size_t ws_size,
                              hipStream_t stream) {
    const float* nbrs = (const float*)d_in[0];
    const float* ref = (const float*)d_in[1];
    float* out = (float*)d_out;

    // slot 4 = ref copy
    copyref_kernel<<<(B_ * C_ * HW_ / 4) / 256, 256, 0, stream>>>(ref, out);

    // main: B*N*(H/2) = 1024 two-row blocks of 256 threads
    localcorr_kernel<<<B_ * N_ * (H_ / 2), 256, 0, stream>>>(nbrs, ref, out);
}

// Round 16
// 67.306 us; speedup vs baseline: 1.1120x; 1.1120x over previous
//
#include <hip/hip_runtime.h>
#include <math.h>

namespace {

constexpr int B_ = 4, N_ = 4, C_ = 64, H_ = 128, W_ = 128;
constexpr int HW_ = H_ * W_;
constexpr int CPB = 4;               // channels per barrier window
constexpr int NWIN = C_ / CPB;       // 16 windows per pass
constexpr int ROWS = 4;              // output rows per block

// out[:, 4] = ref
__global__ __launch_bounds__(256) void copyref_kernel(const float* __restrict__ ref,
                                                      float* __restrict__ out) {
    int t = blockIdx.x * 256 + threadIdx.x;      // one float4 per thread
    int f = t * 4;
    int b = f / (C_ * HW_);
    int within = f - b * (C_ * HW_);
    float4 v = *reinterpret_cast<const float4*>(ref + (size_t)b * C_ * HW_ + within);
    *reinterpret_cast<float4*>(out + (size_t)(b * 5 + N_) * C_ * HW_ + within) = v;
}

__device__ __forceinline__ float2 ld2(const float* p) {
    return *reinterpret_cast<const float2*>(p);
}

// 2 px/thread (aligned float2). Block = 256 threads = 4 rows (wave r = row r).
// Waves 0/1 additionally stage the top/bottom halo rows. Windows of both own
// pixels read as 3 aligned b64 LDS reads per row (left.y | own pair | right.x),
// center row's own pair stays in registers. Norms shared via s_nrm (b64 too).
// grid = B*N*(H/4) = 512 blocks. CPB=4 channels per barrier, double-buffered.
__global__ __launch_bounds__(256) void localcorr_kernel(const float* __restrict__ nbrs,
                                                        const float* __restrict__ ref,
                                                        float* __restrict__ out) {
    __shared__ float2 s_own[2 * CPB][6][64];   // [slot][staged row][float2 col]
    __shared__ float2 s_nrm[6][64];

    const int blk = blockIdx.x;          // 0..511
    const int ytile = blk & 31;          // H/ROWS = 32
    const int bi = blk >> 5;
    const int i = bi & 3;
    const int b = bi >> 2;
    const int t = (int)threadIdx.x;
    const int xh = t & 63;               // float2 col 0..63
    const int ry = t >> 6;               // 0..3 == wave id == row in block
    const int x0 = xh * 2;
    const int y0 = ytile * ROWS;
    const int y = y0 + ry;

    // pair indices implementing x-reflect: x0==0 -> left = pair0.y (col 1);
    // x0==126 -> right = pair63.x (col 126)
    const int xlh = (xh == 0) ? 0 : xh - 1;
    const int xrh = (xh == 63) ? 63 : xh + 1;
    // staged rows 0..5 = global rows refl(y0-1), y0..y0+3, refl(y0+4)
    const int gTop = (y0 == 0) ? 1 : y0 - 1;
    const int gBot = (y0 + ROWS == H_) ? H_ - 2 : y0 + ROWS;

    const bool isHalo = (t < 128);       // waves 0,1 (wave-uniform)
    const int haloRow = (t < 64) ? 0 : 5;
    const int haloOff = ((t < 64) ? gTop : gBot) * W_ + x0;

    const float* __restrict__ nb = nbrs + (size_t)(b * N_ + i) * C_ * HW_;
    const float* __restrict__ rp = ref + (size_t)b * C_ * HW_;
    const int offO = y * W_ + x0;

    float d0[9], d1[9];
#pragma unroll
    for (int k = 0; k < 9; ++k) { d0[k] = 0.f; d1[k] = 0.f; }
    float na = 0.f, nb2 = 0.f, r20 = 0.f, r21 = 0.f, hna = 0.f, hnb = 0.f;

    // ---- pass 1: dots + norms + ref2 ----
    float2 cO[CPB], cR[CPB], cH[CPB];
    float2 nO[CPB], nR[CPB], nH[CPB];
#pragma unroll
    for (int u = 0; u < CPB; ++u) {
        const size_t co = (size_t)u * HW_;
        cO[u] = ld2(nb + co + offO);
        cR[u] = ld2(rp + co + offO);
        cH[u] = isHalo ? ld2(nb + co + haloOff) : make_float2(0.f, 0.f);
        nH[u] = make_float2(0.f, 0.f);
    }
#pragma unroll 1
    for (int w = 0; w < NWIN; ++w) {
        const int base = (w & 1) * CPB;
#pragma unroll
        for (int u = 0; u < CPB; ++u) {
            s_own[base + u][ry + 1][xh] = cO[u];
            if (isHalo) s_own[base + u][haloRow][xh] = cH[u];
        }
        __syncthreads();
        if (w + 1 < NWIN) {
#pragma unroll
            for (int u = 0; u < CPB; ++u) {
                const size_t co = (size_t)((w + 1) * CPB + u) * HW_;
                nO[u] = ld2(nb + co + offO);
                nR[u] = ld2(rp + co + offO);
                if (isHalo) nH[u] = ld2(nb + co + haloOff);
            }
        }
#pragma unroll
        for (int u = 0; u < CPB; ++u) {
            const float2 rf = cR[u];
            r20 += rf.x * rf.x; r21 += rf.y * rf.y;
            na += cO[u].x * cO[u].x; nb2 += cO[u].y * cO[u].y;
            if (isHalo) { hna += cH[u].x * cH[u].x; hnb += cH[u].y * cH[u].y; }
#pragma unroll
            for (int wr = 0; wr < 3; ++wr) {
                const int r = ry + wr;
                const float2 Lp = s_own[base + u][r][xlh];
                const float2 Cp = (wr == 1) ? cO[u] : s_own[base + u][r][xh];
                const float2 Rp = s_own[base + u][r][xrh];
                d0[3 * wr + 0] += rf.x * Lp.y;
                d0[3 * wr + 1] += rf.x * Cp.x;
                d0[3 * wr + 2] += rf.x * Cp.y;
                d1[3 * wr + 0] += rf.y * Cp.x;
                d1[3 * wr + 1] += rf.y * Cp.y;
                d1[3 * wr + 2] += rf.y * Rp.x;
            }
        }
#pragma unroll
        for (int u = 0; u < CPB; ++u) { cO[u] = nO[u]; cR[u] = nR[u]; cH[u] = nH[u]; }
    }

    // ---- share norms (b64), softmax for both pixels ----
    s_nrm[ry + 1][xh] = make_float2(na, nb2);
    if (isHalo) s_nrm[haloRow][xh] = make_float2(hna, hnb);
    __syncthreads();

    float nk0[9], nk1[9];
#pragma unroll
    for (int wr = 0; wr < 3; ++wr) {
        const int r = ry + wr;
        const float2 Lp = s_nrm[r][xlh];
        const float2 Cp = (wr == 1) ? make_float2(na, nb2) : s_nrm[r][xh];
        const float2 Rp = s_nrm[r][xrh];
        nk0[3 * wr + 0] = Lp.y; nk0[3 * wr + 1] = Cp.x; nk0[3 * wr + 2] = Cp.y;
        nk1[3 * wr + 0] = Cp.x; nk1[3 * wr + 1] = Cp.y; nk1[3 * wr + 2] = Rp.x;
    }

    float w0[9], w1[9];
    {
        const float invr = rsqrtf(fmaxf(r20, 1e-24f));
        float iv[9], dd[9];
#pragma unroll
        for (int k = 0; k < 9; ++k) {
            iv[k] = rsqrtf(fmaxf(nk0[k], 1e-24f));
            dd[k] = d0[k] * invr * iv[k];
        }
        float mx = dd[0];
#pragma unroll
        for (int k = 1; k < 9; ++k) mx = fmaxf(mx, dd[k]);
        float ss = 0.f;
#pragma unroll
        for (int k = 0; k < 9; ++k) { dd[k] = __expf(dd[k] - mx); ss += dd[k]; }
        const float is = 1.f / ss;
#pragma unroll
        for (int k = 0; k < 9; ++k) w0[k] = dd[k] * is * iv[k];
    }
    {
        const float invr = rsqrtf(fmaxf(r21, 1e-24f));
        float iv[9], dd[9];
#pragma unroll
        for (int k = 0; k < 9; ++k) {
            iv[k] = rsqrtf(fmaxf(nk1[k], 1e-24f));
            dd[k] = d1[k] * invr * iv[k];
        }
        float mx = dd[0];
#pragma unroll
        for (int k = 1; k < 9; ++k) mx = fmaxf(mx, dd[k]);
        float ss = 0.f;
#pragma unroll
        for (int k = 0; k < 9; ++k) { dd[k] = __expf(dd[k] - mx); ss += dd[k]; }
        const float is = 1.f / ss;
#pragma unroll
        for (int k = 0; k < 9; ++k) w1[k] = dd[k] * is * iv[k];
    }

    // ---- pass 2: aggregate + wdiff + store ----
    const float* __restrict__ pm0 = nbrs + (size_t)(b * N_ + ((i + 1) & 3)) * C_ * HW_;
    const float* __restrict__ pm1 = nbrs + (size_t)(b * N_ + ((i + 2) & 3)) * C_ * HW_;
    const float* __restrict__ pm2 = nbrs + (size_t)(b * N_ + ((i + 3) & 3)) * C_ * HW_;
    float* __restrict__ op = out + (size_t)(b * 5 + i) * C_ * HW_ + offO;

    float2 q0c[CPB], q1c[CPB], q2c[CPB];
    float2 q0n[CPB], q1n[CPB], q2n[CPB];
#pragma unroll
    for (int u = 0; u < CPB; ++u) {
        const size_t co = (size_t)u * HW_;
        cO[u] = ld2(nb + co + offO);
        cH[u] = isHalo ? ld2(nb + co + haloOff) : make_float2(0.f, 0.f);
        q0c[u] = ld2(pm0 + co + offO);
        q1c[u] = ld2(pm1 + co + offO);
        q2c[u] = ld2(pm2 + co + offO);
    }
#pragma unroll 1
    for (int w = 0; w < NWIN; ++w) {
        const int base = (w & 1) * CPB;
#pragma unroll
        for (int u = 0; u < CPB; ++u) {
            s_own[base + u][ry + 1][xh] = cO[u];
            if (isHalo) s_own[base + u][haloRow][xh] = cH[u];
        }
        __syncthreads();
        if (w + 1 < NWIN) {
#pragma unroll
            for (int u = 0; u < CPB; ++u) {
                const size_t co = (size_t)((w + 1) * CPB + u) * HW_;
                nO[u] = ld2(nb + co + offO);
                if (isHalo) nH[u] = ld2(nb + co + haloOff);
                q0n[u] = ld2(pm0 + co + offO);
                q1n[u] = ld2(pm1 + co + offO);
                q2n[u] = ld2(pm2 + co + offO);
            }
        }
#pragma unroll
        for (int u = 0; u < CPB; ++u) {
            float agg0 = 0.f, agg1 = 0.f;
#pragma unroll
            for (int wr = 0; wr < 3; ++wr) {
                const int r = ry + wr;
                const float2 Lp = s_own[base + u][r][xlh];
                const float2 Cp = (wr == 1) ? cO[u] : s_own[base + u][r][xh];
                const float2 Rp = s_own[base + u][r][xrh];
                agg0 += w0[3 * wr + 0] * Lp.y + w0[3 * wr + 1] * Cp.x + w0[3 * wr + 2] * Cp.y;
                agg1 += w1[3 * wr + 0] * Cp.x + w1[3 * wr + 1] * Cp.y + w1[3 * wr + 2] * Rp.x;
            }
            const float2 ctr = cO[u];
            const float s0 = ctr.x + q0c[u].x + q1c[u].x + q2c[u].x;
            const float s1 = ctr.y + q0c[u].y + q1c[u].y + q2c[u].y;
            const float dd0 = ctr.x - 0.25f * s0;
            const float dd1 = ctr.y - 0.25f * s1;
            float2 o2;
            o2.x = agg0 * __expf(-dd0 * dd0);
            o2.y = agg1 * __expf(-dd1 * dd1);
            *reinterpret_cast<float2*>(op + (size_t)(w * CPB + u) * HW_) = o2;
        }
#pragma unroll
        for (int u = 0; u < CPB; ++u) {
            cO[u] = nO[u]; cH[u] = nH[u];
            q0c[u] = q0n[u]; q1c[u] = q1n[u]; q2c[u] = q2n[u];
        }
    }
}

}  // namespace

extern "C" void kernel_launch(void* const* d_in, const int* in_sizes, int n_in,
                              void* d_out, int out_size, void* d_ws, size_t ws_size,
                              hipStream_t stream) {
    const float* nbrs = (const float*)d_in[0];
    const float* ref = (const float*)d_in[1];
    float* out = (float*)d_out;

    // slot 4 = ref copy
    copyref_kernel<<<(B_ * C_ * HW_ / 4) / 256, 256, 0, stream>>>(ref, out);

    // main: B*N*(H/4) = 512 four-row blocks of 256 threads (2 px/thread)
    localcorr_kernel<<<B_ * N_ * (H_ / ROWS), 256, 0, stream>>>(nbrs, ref, out);
}